// Round 4
// baseline (2758.891 us; speedup 1.0000x reference)
//
#include <hip/hip_runtime.h>
#include <stdint.h>

// RNG bits variant for the partitionable threefry path (x0=hi=0, x1=lo=i):
//   0: bits = o0 ^ o1   (current best guess: narrow widths xor both lanes)
//   1: bits = o0
//   2: bits = o1        (tested round 1 -- failed)
#ifndef BITS_MODE
#define BITS_MODE 0
#endif

constexpr int kN    = 100000;   // nodes
constexpr int kDOut = 128;      // output dim
constexpr int kNNZ  = 3200000;  // nnz for both X and A

__device__ __forceinline__ uint32_t rotl32(uint32_t v, int r) {
  return (v << r) | (v >> (32 - r));
}

// Threefry-2x32, 20 rounds (verified vs KAT tf((0,0),(0,0))=(0x6b200159,0x99ba4efe))
__device__ __forceinline__ void threefry2x32(uint32_t k0, uint32_t k1,
                                             uint32_t x0, uint32_t x1,
                                             uint32_t& o0, uint32_t& o1) {
  const uint32_t ks0 = k0, ks1 = k1, ks2 = k0 ^ k1 ^ 0x1BD11BDAu;
  x0 += ks0; x1 += ks1;
#define TF_RND(r) { x0 += x1; x1 = rotl32(x1, (r)); x1 ^= x0; }
  TF_RND(13) TF_RND(15) TF_RND(26) TF_RND(6)
  x0 += ks1; x1 += ks2 + 1u;
  TF_RND(17) TF_RND(29) TF_RND(16) TF_RND(24)
  x0 += ks2; x1 += ks0 + 2u;
  TF_RND(13) TF_RND(15) TF_RND(26) TF_RND(6)
  x0 += ks0; x1 += ks1 + 3u;
  TF_RND(17) TF_RND(29) TF_RND(16) TF_RND(24)
  x0 += ks1; x1 += ks2 + 4u;
  TF_RND(13) TF_RND(15) TF_RND(26) TF_RND(6)
  x0 += ks2; x1 += ks0 + 5u;
#undef TF_RND
  o0 = x0; o1 = x1;
}

__device__ __forceinline__ float bits_to_unit_float(uint32_t bits) {
  // jax _uniform f32: bitcast((bits >> 9) | 0x3f800000) - 1.0
  return __uint_as_float((bits >> 9) | 0x3f800000u) - 1.0f;
}

// xv[i] = x_vals[i] * floor(0.9f + u_i) * (float)(1.0/0.9)
__global__ void dropout_kernel(const float* __restrict__ xval,
                               float* __restrict__ xv, int nnz) {
  int i = blockIdx.x * blockDim.x + threadIdx.x;
  if (i >= nnz) return;
  uint32_t o0, o1;
  // partitionable: count = u64 iota; x0 = hi word (0 for i < 2^32), x1 = lo
  threefry2x32(0u, 42u, 0u, (uint32_t)i, o0, o1);
#if BITS_MODE == 0
  uint32_t bits = o0 ^ o1;
#elif BITS_MODE == 1
  uint32_t bits = o0;
#else
  uint32_t bits = o1;
#endif
  float u = bits_to_unit_float(bits);
  float mask = floorf(0.9f + u);
  xv[i] = xval[i] * mask * (float)(1.0 / 0.9);
}

// h[r, :] += xv[e] * W[c, :]  -- 128 lanes per edge, contiguous atomics
__global__ void spmm1_kernel(const int* __restrict__ rows,
                             const int* __restrict__ cols,
                             const float* __restrict__ xv,
                             const float* __restrict__ W,
                             float* __restrict__ h) {
  long long t = (long long)blockIdx.x * blockDim.x + threadIdx.x;
  int e = (int)(t >> 7);
  int d = (int)(t & 127);
  if (e >= kNNZ) return;
  float v = xv[e];
  if (v == 0.0f) return;  // dropped: contributes nothing
  int r = rows[e], c = cols[e];
  atomicAdd(&h[(size_t)r * kDOut + d], v * W[(size_t)c * kDOut + d]);
}

// out[r, :] += adj_vals[e] * h[c, :]
__global__ void spmm2_kernel(const int* __restrict__ rows,
                             const int* __restrict__ cols,
                             const float* __restrict__ vals,
                             const float* __restrict__ h,
                             float* __restrict__ out) {
  long long t = (long long)blockIdx.x * blockDim.x + threadIdx.x;
  int e = (int)(t >> 7);
  int d = (int)(t & 127);
  if (e >= kNNZ) return;
  int r = rows[e], c = cols[e];
  atomicAdd(&out[(size_t)r * kDOut + d], vals[e] * h[(size_t)c * kDOut + d]);
}

__global__ void relu_kernel(float* __restrict__ out, int n) {
  int i = blockIdx.x * blockDim.x + threadIdx.x;
  if (i < n) out[i] = fmaxf(out[i], 0.0f);
}

extern "C" void kernel_launch(void* const* d_in, const int* in_sizes, int n_in,
                              void* d_out, int out_size, void* d_ws, size_t ws_size,
                              hipStream_t stream) {
  const int*   x_rows   = (const int*)d_in[0];
  const int*   x_cols   = (const int*)d_in[1];
  const float* x_vals   = (const float*)d_in[2];
  const int*   adj_rows = (const int*)d_in[3];
  const int*   adj_cols = (const int*)d_in[4];
  const float* adj_vals = (const float*)d_in[5];
  const float* W        = (const float*)d_in[6];
  float* out = (float*)d_out;

  // workspace: xv [kNNZ] f32, then h [kN * kDOut] f32  (64 MB total)
  float* xv = (float*)d_ws;
  float* h  = (float*)((char*)d_ws + (size_t)kNNZ * sizeof(float));

  const size_t hBytes = (size_t)kN * kDOut * sizeof(float);
  hipMemsetAsync(h, 0, hBytes, stream);
  hipMemsetAsync(out, 0, hBytes, stream);

  dropout_kernel<<<(kNNZ + 255) / 256, 256, 0, stream>>>(x_vals, xv, kNNZ);

  const unsigned spmmBlocks = (unsigned)(((long long)kNNZ * kDOut) / 256);
  spmm1_kernel<<<spmmBlocks, 256, 0, stream>>>(x_rows, x_cols, xv, W, h);
  spmm2_kernel<<<spmmBlocks, 256, 0, stream>>>(adj_rows, adj_cols, adj_vals, h, out);
  relu_kernel<<<(kN * kDOut + 255) / 256, 256, 0, stream>>>(out, kN * kDOut);
}

// Round 5
// 1277.233 us; speedup vs baseline: 2.1601x; 2.1601x over previous
//
#include <hip/hip_runtime.h>
#include <stdint.h>

constexpr int kN    = 100000;   // nodes
constexpr int kDOut = 128;      // output dim
constexpr int kNNZ  = 3200000;  // nnz for both X and A
constexpr float kInvKeep = (float)(1.0 / 0.9);

// ---------------- RNG (verified round 4: partitionable, bits = o0^o1) -----
__device__ __forceinline__ uint32_t rotl32(uint32_t v, int r) {
  return (v << r) | (v >> (32 - r));
}
__device__ __forceinline__ void threefry2x32(uint32_t k0, uint32_t k1,
                                             uint32_t x0, uint32_t x1,
                                             uint32_t& o0, uint32_t& o1) {
  const uint32_t ks0 = k0, ks1 = k1, ks2 = k0 ^ k1 ^ 0x1BD11BDAu;
  x0 += ks0; x1 += ks1;
#define TF_RND(r) { x0 += x1; x1 = rotl32(x1, (r)); x1 ^= x0; }
  TF_RND(13) TF_RND(15) TF_RND(26) TF_RND(6)
  x0 += ks1; x1 += ks2 + 1u;
  TF_RND(17) TF_RND(29) TF_RND(16) TF_RND(24)
  x0 += ks2; x1 += ks0 + 2u;
  TF_RND(13) TF_RND(15) TF_RND(26) TF_RND(6)
  x0 += ks0; x1 += ks1 + 3u;
  TF_RND(17) TF_RND(29) TF_RND(16) TF_RND(24)
  x0 += ks1; x1 += ks2 + 4u;
  TF_RND(13) TF_RND(15) TF_RND(26) TF_RND(6)
  x0 += ks2; x1 += ks0 + 5u;
#undef TF_RND
  o0 = x0; o1 = x1;
}
// keep mask in {0,1} for element i, exactly as validated in round 4
__device__ __forceinline__ float keep_mask(uint32_t i) {
  uint32_t o0, o1;
  threefry2x32(0u, 42u, 0u, i, o0, o1);
  uint32_t bits = o0 ^ o1;
  float u = __uint_as_float((bits >> 9) | 0x3f800000u) - 1.0f;
  return floorf(0.9f + u);
}

// ---------------- CSR build: histogram -> scan -> scatter ------------------
template<bool DROPOUT>
__global__ void hist_kernel(const int* __restrict__ rows, int* __restrict__ cnt,
                            int nnz) {
  int e = blockIdx.x * blockDim.x + threadIdx.x;
  if (e >= nnz) return;
  if (DROPOUT && keep_mask((uint32_t)e) == 0.0f) return;
  atomicAdd(&cnt[rows[e]], 1);
}

// 2-level exclusive scan over cnt[0..n) -> rowptr[0..n), rowptr[n]=total
constexpr int kScanChunk = 2048;   // 256 threads x 8 elems
constexpr int kScanBlk   = (kN + kScanChunk - 1) / kScanChunk;  // 49

__global__ void scan1_kernel(const int* __restrict__ cnt, int* __restrict__ rowptr,
                             int* __restrict__ partials, int n) {
  __shared__ int sd[256];
  int b = blockIdx.x, t = threadIdx.x;
  int base = b * kScanChunk + t * 8;
  int v[8]; int s = 0;
  #pragma unroll
  for (int k = 0; k < 8; ++k) { int idx = base + k; v[k] = (idx < n) ? cnt[idx] : 0; s += v[k]; }
  sd[t] = s; __syncthreads();
  #pragma unroll
  for (int off = 1; off < 256; off <<= 1) {
    int x = (t >= off) ? sd[t - off] : 0;
    __syncthreads();
    sd[t] += x;
    __syncthreads();
  }
  if (t == 255) partials[b] = sd[255];
  int run = (t == 0) ? 0 : sd[t - 1];
  #pragma unroll
  for (int k = 0; k < 8; ++k) { int idx = base + k; if (idx < n) rowptr[idx] = run; run += v[k]; }
}

__global__ void scan2_kernel(int* __restrict__ partials, int* __restrict__ rowptr,
                             int nblk, int n) {
  __shared__ int sd[64];
  int t = threadIdx.x;
  sd[t] = (t < nblk) ? partials[t] : 0;
  __syncthreads();
  #pragma unroll
  for (int off = 1; off < 64; off <<= 1) {
    int x = (t >= off) ? sd[t - off] : 0;
    __syncthreads();
    sd[t] += x;
    __syncthreads();
  }
  if (t < nblk) partials[t] = (t == 0) ? 0 : sd[t - 1];
  if (t == 63) rowptr[n] = sd[63];   // total
}

__global__ void scan3_kernel(int* __restrict__ rowptr, const int* __restrict__ partials,
                             int n) {
  int i = blockIdx.x * blockDim.x + threadIdx.x;
  if (i < n) rowptr[i] += partials[i / kScanChunk];
}

template<bool DROPOUT>
__global__ void scatter_kernel(const int* __restrict__ rows, const int* __restrict__ cols,
                               const float* __restrict__ vals,
                               const int* __restrict__ rowptr, int* __restrict__ cur,
                               int* __restrict__ scols, float* __restrict__ svals,
                               int nnz) {
  int e = blockIdx.x * blockDim.x + threadIdx.x;
  if (e >= nnz) return;
  float scale = 1.0f;
  if (DROPOUT) {
    if (keep_mask((uint32_t)e) == 0.0f) return;
    scale = kInvKeep;
  }
  int r = rows[e];
  int pos = rowptr[r] + atomicAdd(&cur[r], 1);
  scols[pos] = cols[e];
  svals[pos] = vals[e] * scale;
}

// ---------------- CSR SpMM: 2 rows per 256-thread block --------------------
template<bool RELU>
__global__ void spmm_csr_kernel(const int* __restrict__ rowptr,
                                const int* __restrict__ cols,
                                const float* __restrict__ vals,
                                const float* __restrict__ B,   // [*, kDOut]
                                float* __restrict__ out, int nrows) {
  int tid = threadIdx.x;
  int row = blockIdx.x * 2 + (tid >> 7);
  int d = tid & 127;
  if (row >= nrows) return;
  int e = rowptr[row], e_end = rowptr[row + 1];
  float acc = 0.0f;
  for (; e + 1 < e_end; e += 2) {
    int c0 = cols[e], c1 = cols[e + 1];
    float v0 = vals[e], v1 = vals[e + 1];
    acc += v0 * B[(size_t)c0 * kDOut + d];
    acc += v1 * B[(size_t)c1 * kDOut + d];
  }
  if (e < e_end) acc += vals[e] * B[(size_t)cols[e] * kDOut + d];
  if (RELU) acc = fmaxf(acc, 0.0f);
  out[(size_t)row * kDOut + d] = acc;
}

// ---------------- Fallback (round-4 validated atomic path) -----------------
__global__ void dropout_kernel(const float* __restrict__ xval,
                               float* __restrict__ xv, int nnz) {
  int i = blockIdx.x * blockDim.x + threadIdx.x;
  if (i >= nnz) return;
  xv[i] = xval[i] * keep_mask((uint32_t)i) * kInvKeep;
}
__global__ void spmm1_atomic(const int* __restrict__ rows, const int* __restrict__ cols,
                             const float* __restrict__ xv, const float* __restrict__ W,
                             float* __restrict__ h) {
  long long t = (long long)blockIdx.x * blockDim.x + threadIdx.x;
  int e = (int)(t >> 7), d = (int)(t & 127);
  if (e >= kNNZ) return;
  float v = xv[e];
  if (v == 0.0f) return;
  atomicAdd(&h[(size_t)rows[e] * kDOut + d], v * W[(size_t)cols[e] * kDOut + d]);
}
__global__ void spmm2_atomic(const int* __restrict__ rows, const int* __restrict__ cols,
                             const float* __restrict__ vals, const float* __restrict__ h,
                             float* __restrict__ out) {
  long long t = (long long)blockIdx.x * blockDim.x + threadIdx.x;
  int e = (int)(t >> 7), d = (int)(t & 127);
  if (e >= kNNZ) return;
  atomicAdd(&out[(size_t)rows[e] * kDOut + d], vals[e] * h[(size_t)cols[e] * kDOut + d]);
}
__global__ void relu_kernel(float* __restrict__ out, int n) {
  int i = blockIdx.x * blockDim.x + threadIdx.x;
  if (i < n) out[i] = fmaxf(out[i], 0.0f);
}

// ---------------------------------------------------------------------------
extern "C" void kernel_launch(void* const* d_in, const int* in_sizes, int n_in,
                              void* d_out, int out_size, void* d_ws, size_t ws_size,
                              hipStream_t stream) {
  const int*   x_rows   = (const int*)d_in[0];
  const int*   x_cols   = (const int*)d_in[1];
  const float* x_vals   = (const float*)d_in[2];
  const int*   adj_rows = (const int*)d_in[3];
  const int*   adj_cols = (const int*)d_in[4];
  const float* adj_vals = (const float*)d_in[5];
  const float* W        = (const float*)d_in[6];
  float* out = (float*)d_out;

  const size_t hBytes = (size_t)kN * kDOut * sizeof(float);

  // workspace layout (256B-aligned chunks)
  size_t off = 0;
  auto take = [&](size_t bytes) -> char* {
    char* p = (char*)d_ws + off;
    off += (bytes + 255) & ~(size_t)255;
    return p;
  };
  float* h        = (float*)take(hBytes);                    // 51.2 MB
  int*   rowptr   = (int*)take((size_t)(kN + 1) * 4);        // 400 KB
  int*   cur      = (int*)take((size_t)kN * 4);              // 400 KB
  int*   scols    = (int*)take((size_t)kNNZ * 4);            // 12.8 MB
  float* svals    = (float*)take((size_t)kNNZ * 4);          // 12.8 MB
  int*   partials = (int*)take(64 * 4);
  const size_t needed = off;                                 // ~77.7 MB

  const int histBlocks = (kNNZ + 255) / 256;
  const int spmmBlocks = (kN + 1) / 2;

  if (ws_size >= needed) {
    // ---------- X: CSR build (dropout folded in) + spmm1 ----------
    hipMemsetAsync(cur, 0, (size_t)kN * 4, stream);
    hist_kernel<true><<<histBlocks, 256, 0, stream>>>(x_rows, cur, kNNZ);
    scan1_kernel<<<kScanBlk, 256, 0, stream>>>(cur, rowptr, partials, kN);
    scan2_kernel<<<1, 64, 0, stream>>>(partials, rowptr, kScanBlk, kN);
    scan3_kernel<<<(kN + 255) / 256, 256, 0, stream>>>(rowptr, partials, kN);
    hipMemsetAsync(cur, 0, (size_t)kN * 4, stream);
    scatter_kernel<true><<<histBlocks, 256, 0, stream>>>(
        x_rows, x_cols, x_vals, rowptr, cur, scols, svals, kNNZ);
    spmm_csr_kernel<false><<<spmmBlocks, 256, 0, stream>>>(
        rowptr, scols, svals, W, h, kN);

    // ---------- adj: CSR build (reuse buffers) + spmm2(+relu) ----------
    hipMemsetAsync(cur, 0, (size_t)kN * 4, stream);
    hist_kernel<false><<<histBlocks, 256, 0, stream>>>(adj_rows, cur, kNNZ);
    scan1_kernel<<<kScanBlk, 256, 0, stream>>>(cur, rowptr, partials, kN);
    scan2_kernel<<<1, 64, 0, stream>>>(partials, rowptr, kScanBlk, kN);
    scan3_kernel<<<(kN + 255) / 256, 256, 0, stream>>>(rowptr, partials, kN);
    hipMemsetAsync(cur, 0, (size_t)kN * 4, stream);
    scatter_kernel<false><<<histBlocks, 256, 0, stream>>>(
        adj_rows, adj_cols, adj_vals, rowptr, cur, scols, svals, kNNZ);
    spmm_csr_kernel<true><<<spmmBlocks, 256, 0, stream>>>(
        rowptr, scols, svals, h, out, kN);
  } else {
    // ---------- fallback: round-4 validated atomic path (needs 64 MB) ----
    float* xv = (float*)d_ws;
    float* hh = (float*)((char*)d_ws + (size_t)kNNZ * sizeof(float));
    hipMemsetAsync(hh, 0, hBytes, stream);
    hipMemsetAsync(out, 0, hBytes, stream);
    dropout_kernel<<<histBlocks, 256, 0, stream>>>(x_vals, xv, kNNZ);
    const unsigned eb = (unsigned)(((long long)kNNZ * kDOut) / 256);
    spmm1_atomic<<<eb, 256, 0, stream>>>(x_rows, x_cols, xv, W, hh);
    spmm2_atomic<<<eb, 256, 0, stream>>>(adj_rows, adj_cols, adj_vals, hh, out);
    relu_kernel<<<(kN * kDOut + 255) / 256, 256, 0, stream>>>(out, kN * kDOut);
  }
}

// Round 6
// 893.491 us; speedup vs baseline: 3.0878x; 1.4295x over previous
//
#include <hip/hip_runtime.h>
#include <stdint.h>

constexpr int kN    = 100000;   // nodes
constexpr int kDOut = 128;      // output dim
constexpr int kDIn  = 256;      // input feature dim
constexpr int kNNZ  = 3200000;  // nnz for both X and A
constexpr float kInvKeep = (float)(1.0 / 0.9);

// ---------------- RNG (verified round 4: partitionable, bits = o0^o1) -----
__device__ __forceinline__ uint32_t rotl32(uint32_t v, int r) {
  return (v << r) | (v >> (32 - r));
}
__device__ __forceinline__ void threefry2x32(uint32_t k0, uint32_t k1,
                                             uint32_t x0, uint32_t x1,
                                             uint32_t& o0, uint32_t& o1) {
  const uint32_t ks0 = k0, ks1 = k1, ks2 = k0 ^ k1 ^ 0x1BD11BDAu;
  x0 += ks0; x1 += ks1;
#define TF_RND(r) { x0 += x1; x1 = rotl32(x1, (r)); x1 ^= x0; }
  TF_RND(13) TF_RND(15) TF_RND(26) TF_RND(6)
  x0 += ks1; x1 += ks2 + 1u;
  TF_RND(17) TF_RND(29) TF_RND(16) TF_RND(24)
  x0 += ks2; x1 += ks0 + 2u;
  TF_RND(13) TF_RND(15) TF_RND(26) TF_RND(6)
  x0 += ks0; x1 += ks1 + 3u;
  TF_RND(17) TF_RND(29) TF_RND(16) TF_RND(24)
  x0 += ks1; x1 += ks2 + 4u;
  TF_RND(13) TF_RND(15) TF_RND(26) TF_RND(6)
  x0 += ks2; x1 += ks0 + 5u;
#undef TF_RND
  o0 = x0; o1 = x1;
}
__device__ __forceinline__ float keep_mask(uint32_t i) {
  uint32_t o0, o1;
  threefry2x32(0u, 42u, 0u, i, o0, o1);
  uint32_t bits = o0 ^ o1;
  float u = __uint_as_float((bits >> 9) | 0x3f800000u) - 1.0f;
  return floorf(0.9f + u);
}

// ---------------- bf16 helpers (RTNE) --------------------------------------
__device__ __forceinline__ uint16_t f32_to_bf16(float f) {
  uint32_t u = __float_as_uint(f);
  u += 0x7fffu + ((u >> 16) & 1u);
  return (uint16_t)(u >> 16);
}
__device__ __forceinline__ float bf16lo_to_f32(uint32_t packed) {
  return __uint_as_float(packed << 16);
}
__device__ __forceinline__ float bf16hi_to_f32(uint32_t packed) {
  return __uint_as_float(packed & 0xffff0000u);
}

// ---------------- CSR build: histogram -> scan -> scatter ------------------
template<bool DROPOUT>
__global__ void hist_kernel(const int* __restrict__ rows, int* __restrict__ cnt,
                            int nnz) {
  int e = blockIdx.x * blockDim.x + threadIdx.x;
  if (e >= nnz) return;
  if (DROPOUT && keep_mask((uint32_t)e) == 0.0f) return;
  atomicAdd(&cnt[rows[e]], 1);
}

constexpr int kScanChunk = 2048;   // 256 threads x 8 elems
constexpr int kScanBlk   = (kN + kScanChunk - 1) / kScanChunk;  // 49

__global__ void scan1_kernel(const int* __restrict__ cnt, int* __restrict__ rowptr,
                             int* __restrict__ partials, int n) {
  __shared__ int sd[256];
  int b = blockIdx.x, t = threadIdx.x;
  int base = b * kScanChunk + t * 8;
  int v[8]; int s = 0;
  #pragma unroll
  for (int k = 0; k < 8; ++k) { int idx = base + k; v[k] = (idx < n) ? cnt[idx] : 0; s += v[k]; }
  sd[t] = s; __syncthreads();
  #pragma unroll
  for (int off = 1; off < 256; off <<= 1) {
    int x = (t >= off) ? sd[t - off] : 0;
    __syncthreads();
    sd[t] += x;
    __syncthreads();
  }
  if (t == 255) partials[b] = sd[255];
  int run = (t == 0) ? 0 : sd[t - 1];
  #pragma unroll
  for (int k = 0; k < 8; ++k) { int idx = base + k; if (idx < n) rowptr[idx] = run; run += v[k]; }
}

__global__ void scan2_kernel(int* __restrict__ partials, int* __restrict__ rowptr,
                             int nblk, int n) {
  __shared__ int sd[64];
  int t = threadIdx.x;
  sd[t] = (t < nblk) ? partials[t] : 0;
  __syncthreads();
  #pragma unroll
  for (int off = 1; off < 64; off <<= 1) {
    int x = (t >= off) ? sd[t - off] : 0;
    __syncthreads();
    sd[t] += x;
    __syncthreads();
  }
  if (t < nblk) partials[t] = (t == 0) ? 0 : sd[t - 1];
  if (t == 63) rowptr[n] = sd[63];
}

__global__ void scan3_kernel(int* __restrict__ rowptr, const int* __restrict__ partials,
                             int n) {
  int i = blockIdx.x * blockDim.x + threadIdx.x;
  if (i < n) rowptr[i] += partials[i / kScanChunk];
}

// scatter packed (col, val_bits) -> single 8B store per edge
template<bool DROPOUT>
__global__ void scatter_kernel(const int* __restrict__ rows, const int* __restrict__ cols,
                               const float* __restrict__ vals,
                               const int* __restrict__ rowptr, int* __restrict__ cur,
                               uint2* __restrict__ spack, int nnz) {
  int e = blockIdx.x * blockDim.x + threadIdx.x;
  if (e >= nnz) return;
  float scale = 1.0f;
  if (DROPOUT) {
    if (keep_mask((uint32_t)e) == 0.0f) return;
    scale = kInvKeep;
  }
  int r = rows[e];
  int pos = rowptr[r] + atomicAdd(&cur[r], 1);
  uint2 p;
  p.x = (uint32_t)cols[e];
  p.y = __float_as_uint(vals[e] * scale);
  spack[pos] = p;
}

// ---------------- W (f32, [kDIn][kDOut]) -> bf16 copy ----------------------
__global__ void wcvt_kernel(const float* __restrict__ W, uint16_t* __restrict__ Wb) {
  int i = blockIdx.x * blockDim.x + threadIdx.x;
  if (i < kDIn * kDOut) Wb[i] = f32_to_bf16(W[i]);
}

// ---------------- CSR SpMM, bf16 B-matrix ----------------------------------
// 4 rows per 256-thread block; 64 lanes/row; each lane computes d = 2*lane,
// 2*lane+1 via one 4B bf16x2 gather per edge. OUT_BF16: write h as bf16x2
// (one u32 store); else f32x2 (+ optional ReLU).
template<bool OUT_BF16, bool RELU>
__global__ void spmm_csr_kernel(const int* __restrict__ rowptr,
                                const uint2* __restrict__ spack,
                                const uint16_t* __restrict__ B,  // bf16 [*, kDOut]
                                void* __restrict__ outv, int nrows) {
  int tid = threadIdx.x;
  int row = blockIdx.x * 4 + (tid >> 6);
  int lane = tid & 63;
  if (row >= nrows) return;
  int e = rowptr[row], e_end = rowptr[row + 1];
  float a0 = 0.0f, a1 = 0.0f;
  const int doff = lane * 2;
  for (; e + 1 < e_end; e += 2) {
    uint2 p0 = spack[e], p1 = spack[e + 1];
    float v0 = __uint_as_float(p0.y);
    float v1 = __uint_as_float(p1.y);
    uint32_t g0 = *(const uint32_t*)(B + (size_t)p0.x * kDOut + doff);
    uint32_t g1 = *(const uint32_t*)(B + (size_t)p1.x * kDOut + doff);
    a0 += v0 * bf16lo_to_f32(g0);
    a1 += v0 * bf16hi_to_f32(g0);
    a0 += v1 * bf16lo_to_f32(g1);
    a1 += v1 * bf16hi_to_f32(g1);
  }
  if (e < e_end) {
    uint2 p0 = spack[e];
    float v0 = __uint_as_float(p0.y);
    uint32_t g0 = *(const uint32_t*)(B + (size_t)p0.x * kDOut + doff);
    a0 += v0 * bf16lo_to_f32(g0);
    a1 += v0 * bf16hi_to_f32(g0);
  }
  if (RELU) { a0 = fmaxf(a0, 0.0f); a1 = fmaxf(a1, 0.0f); }
  if (OUT_BF16) {
    uint32_t packed = (uint32_t)f32_to_bf16(a0) | ((uint32_t)f32_to_bf16(a1) << 16);
    ((uint32_t*)outv)[(size_t)row * (kDOut / 2) + lane] = packed;
  } else {
    float2 o; o.x = a0; o.y = a1;
    ((float2*)outv)[(size_t)row * (kDOut / 2) + lane] = o;
  }
}

// ---------------------------------------------------------------------------
extern "C" void kernel_launch(void* const* d_in, const int* in_sizes, int n_in,
                              void* d_out, int out_size, void* d_ws, size_t ws_size,
                              hipStream_t stream) {
  const int*   x_rows   = (const int*)d_in[0];
  const int*   x_cols   = (const int*)d_in[1];
  const float* x_vals   = (const float*)d_in[2];
  const int*   adj_rows = (const int*)d_in[3];
  const int*   adj_cols = (const int*)d_in[4];
  const float* adj_vals = (const float*)d_in[5];
  const float* W        = (const float*)d_in[6];
  float* out = (float*)d_out;

  // workspace layout (256B-aligned chunks)
  size_t off = 0;
  auto take = [&](size_t bytes) -> char* {
    char* p = (char*)d_ws + off;
    off += (bytes + 255) & ~(size_t)255;
    return p;
  };
  uint16_t* hb     = (uint16_t*)take((size_t)kN * kDOut * 2);   // 25.6 MB (bf16 h)
  uint16_t* Wb     = (uint16_t*)take((size_t)kDIn * kDOut * 2); // 64 KB
  int*      rowptr = (int*)take((size_t)(kN + 1) * 4);          // 400 KB
  int*      cur    = (int*)take((size_t)kN * 4);                // 400 KB
  uint2*    spack  = (uint2*)take((size_t)kNNZ * 8);            // 25.6 MB
  int*      partials = (int*)take(64 * 4);
  const size_t needed = off;                                    // ~52.3 MB
  if (ws_size < needed) return;

  const int histBlocks = (kNNZ + 255) / 256;
  const int spmmBlocks = (kN + 3) / 4;

  // W -> bf16 (independent of everything below)
  wcvt_kernel<<<(kDIn * kDOut + 255) / 256, 256, 0, stream>>>(W, Wb);

  // ---------- X: CSR build (dropout folded) + spmm1 -> hb ----------
  hipMemsetAsync(cur, 0, (size_t)kN * 4, stream);
  hist_kernel<true><<<histBlocks, 256, 0, stream>>>(x_rows, cur, kNNZ);
  scan1_kernel<<<kScanBlk, 256, 0, stream>>>(cur, rowptr, partials, kN);
  scan2_kernel<<<1, 64, 0, stream>>>(partials, rowptr, kScanBlk, kN);
  scan3_kernel<<<(kN + 255) / 256, 256, 0, stream>>>(rowptr, partials, kN);
  hipMemsetAsync(cur, 0, (size_t)kN * 4, stream);
  scatter_kernel<true><<<histBlocks, 256, 0, stream>>>(
      x_rows, x_cols, x_vals, rowptr, cur, spack, kNNZ);
  spmm_csr_kernel<true, false><<<spmmBlocks, 256, 0, stream>>>(
      rowptr, spack, Wb, hb, kN);

  // ---------- adj: CSR build (reuse buffers) + spmm2(+relu) -> out ----------
  hipMemsetAsync(cur, 0, (size_t)kN * 4, stream);
  hist_kernel<false><<<histBlocks, 256, 0, stream>>>(adj_rows, cur, kNNZ);
  scan1_kernel<<<kScanBlk, 256, 0, stream>>>(cur, rowptr, partials, kN);
  scan2_kernel<<<1, 64, 0, stream>>>(partials, rowptr, kScanBlk, kN);
  scan3_kernel<<<(kN + 255) / 256, 256, 0, stream>>>(rowptr, partials, kN);
  hipMemsetAsync(cur, 0, (size_t)kN * 4, stream);
  scatter_kernel<false><<<histBlocks, 256, 0, stream>>>(
      adj_rows, adj_cols, adj_vals, rowptr, cur, spack, kNNZ);
  spmm_csr_kernel<false, true><<<spmmBlocks, 256, 0, stream>>>(
      rowptr, spack, hb, out, kN);
}